// Round 10
// baseline (169.269 us; speedup 1.0000x reference)
//
#include <hip/hip_runtime.h>
#include <hip/hip_bf16.h>

typedef __attribute__((ext_vector_type(8))) short short8;
typedef __attribute__((ext_vector_type(4))) short short4v;
typedef __attribute__((ext_vector_type(4))) float floatx4;

#define SEQ   2048
#define EMB   1024
#define HEAD  64
#define BATCH 8

// bf16 via round-half-up (2 VALU ops; ties P=2^-16, stats == RNE)
__device__ __forceinline__ short f2bf(float f) {
    union { float f; unsigned u; } a; a.f = f;
    return (short)((a.u + 0x8000u) >> 16);
}

__device__ __forceinline__ short8 pk8(floatx4 a, floatx4 b) {
    short8 r;
    #pragma unroll
    for (int i = 0; i < 4; ++i) {
        union { float f; unsigned u; } x1, x2;
        x1.f = a[i]; x2.f = b[i];
        r[i]     = (short)((x1.u + 0x8000u) >> 16);
        r[4 + i] = (short)((x2.u + 0x8000u) >> 16);
    }
    return r;
}

// async global->LDS, 16B per lane; LDS dst = uniform base + lane*16
__device__ __forceinline__ void gld16(const void* g, void* l) {
    __builtin_amdgcn_global_load_lds(
        (const __attribute__((address_space(1))) unsigned int*)g,
        (__attribute__((address_space(3))) unsigned int*)l,
        16, 0, 0);
}

// Wf layout (chunk-major so one wave's 3 frags are contiguous per chunk):
// fid = chunk*12 + mnt, mnt = mat*4 + nt (mat 0=Wq 1=Wk 2=Wv).
// Wf[fid*512 + lane*8 + j] = W[k=chunk*32+(lane>>4)*8+j][h=nt*16+(lane&15)]
__global__ void wtrans_kernel(const float* __restrict__ Wk,
                              const float* __restrict__ Wq,
                              const float* __restrict__ Wv,
                              short* __restrict__ Wf) {
    int gid  = blockIdx.x * 256 + threadIdx.x;   // 24576 total
    int lane = gid & 63;
    int fid  = gid >> 6;                          // 0..383
    int chunk = fid / 12;
    int mnt  = fid - chunk * 12;
    int mat  = mnt >> 2, nt = mnt & 3;
    const float* src = (mat == 0) ? Wq : (mat == 1) ? Wk : Wv;
    int n = lane & 15, quad = lane >> 4;
    int h = nt * 16 + n;
    short8 o8;
    #pragma unroll
    for (int j = 0; j < 8; ++j)
        o8[j] = f2bf(src[(chunk * 32 + quad * 8 + j) * 64 + h]);
    *(short8*)(Wf + (long)gid * 8) = o8;
}

// QKV: grid 1024 x 256. Block = 16 rows; wave w owns n-tiles 3w..3w+2, FULL K.
// No LDS, no barriers, no reduction. x addresses identical across the 4 waves
// (L1 broadcast -> HBM reads x once); Wf = 3 KB/wave-iter streamed from L2.
// 16 waves/CU for latency hiding.
__global__ __launch_bounds__(256, 4) void qkv_kernel(const float* __restrict__ x,
                                                     const short* __restrict__ Wf,
                                                     short* __restrict__ q,
                                                     short* __restrict__ k,
                                                     short* __restrict__ vt) {
    const int wv   = threadIdx.x >> 6;
    const int lane = threadIdx.x & 63;
    const int l15  = lane & 15;
    const int quad = lane >> 4;
    const int row0 = blockIdx.x * 16;
    const int mnt0 = wv * 3;

    floatx4 acc[3];
    #pragma unroll
    for (int i = 0; i < 3; ++i) acc[i] = (floatx4){0.f, 0.f, 0.f, 0.f};

    const float* xrow  = x + (long)(row0 + l15) * EMB + quad * 8;
    const short* wbase = Wf + ((long)mnt0 * 64 + lane) * 8;

    #pragma unroll 2
    for (int c = 0; c < 32; ++c) {
        const float* xp = xrow + c * 32;
        floatx4 xa = *(const floatx4*)(xp);
        floatx4 xb = *(const floatx4*)(xp + 4);
        const short* wp = wbase + (long)c * 12 * 512;
        short8 b0 = *(const short8*)(wp);
        short8 b1 = *(const short8*)(wp + 512);
        short8 b2 = *(const short8*)(wp + 1024);
        short8 a = pk8(xa, xb);
        acc[0] = __builtin_amdgcn_mfma_f32_16x16x32_bf16(a, b0, acc[0], 0, 0, 0);
        acc[1] = __builtin_amdgcn_mfma_f32_16x16x32_bf16(a, b1, acc[1], 0, 0, 0);
        acc[2] = __builtin_amdgcn_mfma_f32_16x16x32_bf16(a, b2, acc[2], 0, 0, 0);
    }

    const int bidx = row0 >> 11;
    #pragma unroll
    for (int i = 0; i < 3; ++i) {
        const int mnt = mnt0 + i;
        const int mat = mnt >> 2, ntl = mnt & 3;
        const int col = ntl * 16 + l15;
        const long rbase = row0 + quad * 4;
        if (mat == 0) {
            #pragma unroll
            for (int r = 0; r < 4; ++r)
                q[(rbase + r) * HEAD + col] = f2bf(acc[i][r]);
        } else if (mat == 1) {
            #pragma unroll
            for (int r = 0; r < 4; ++r)
                k[(rbase + r) * HEAD + col] = f2bf(acc[i][r]);
        } else {
            short4v vv;
            #pragma unroll
            for (int r = 0; r < 4; ++r) vv[r] = f2bf(acc[i][r]);
            const int srow = (int)(rbase & (SEQ - 1));
            *(short4v*)(vt + ((long)bidx * HEAD + col) * SEQ + srow) = vv;
        }
    }
}

// Attention: 512 blocks = (b, tile t of 32 q-rows), large-t dispatched first.
// 4 waves = (row-group rg) x (key-half kh); K/V BK=64 chunk staged to LDS
// (double-buffered via global_load_lds), shared by all 4 waves. Fixed-base
// softmax exp(s/8-16) (causal diag => row-max >= 0; base cancels in
// sum(pV)/sum(p)); key-half merge is a plain sum. 2 blocks/CU.
__global__ __launch_bounds__(256, 2) void attn_kernel(const short* __restrict__ q,
                                                      const short* __restrict__ k,
                                                      const short* __restrict__ vt,
                                                      float* __restrict__ out) {
    __shared__ short KV[2][16][64][8];     // 32 KB: fid 0-7 K-frags, 8-15 V-frags
    __shared__ short Plds[4][16][40];      // 5 KB
    __shared__ float oT[2][16][64];        // 8 KB [rg][row][col] (kh=1 partials)
    __shared__ float lT[2][16];

    const int wv   = threadIdx.x >> 6;
    const int lane = threadIdx.x & 63;
    const int l15  = lane & 15;
    const int quad = lane >> 4;
    const int rg   = wv & 1;               // row-group within 32-row tile
    const int kh   = wv >> 1;              // key-half within BK=64 chunk
    const int b    = blockIdx.x & 7;
    const int t    = 63 - (blockIdx.x >> 3);   // large tiles dispatch first
    const int s0   = t * 32;
    const int nch  = (t + 2) >> 1;         // ceil(32(t+1)/64)

    const short* kbase = k  + (long)b * SEQ * HEAD;
    const short* vbase = vt + (long)b * HEAD * SEQ;

    const short* qp = q + ((long)b * SEQ + s0 + rg * 16 + l15) * HEAD + quad * 8;
    short8 qf0 = *(const short8*)(qp), qf1 = *(const short8*)(qp + 32);

    floatx4 o[4];
    #pragma unroll
    for (int nh = 0; nh < 4; ++nh) o[nh] = (floatx4){0.f, 0.f, 0.f, 0.f};
    float l_i[4] = {0.f, 0.f, 0.f, 0.f};

    auto stage = [&](int ch, int bb) {
        const int j0 = ch * 64;
        #pragma unroll
        for (int i = 0; i < 2; ++i) {
            const int fid = wv + i * 4;            // K frag: (ntg<<1)|ks
            const int ntg = fid >> 1, ks = fid & 1;
            gld16(kbase + (long)(j0 + ntg * 16 + l15) * HEAD + ks * 32 + quad * 8,
                  &KV[bb][fid][0][0]);
        }
        #pragma unroll
        for (int i = 0; i < 2; ++i) {
            const int fid = wv + i * 4;            // V frag: kh2*4 + nth
            const int kh2 = fid >> 2, nth = fid & 3;
            gld16(vbase + (long)(nth * 16 + l15) * SEQ + j0 + kh2 * 32 + quad * 8,
                  &KV[bb][8 + fid][0][0]);
        }
    };

    stage(0, 0);
    __syncthreads();

    #pragma unroll 1
    for (int ch = 0; ch < nch; ++ch) {
        const int bb = ch & 1;
        if (ch + 1 < nch) stage(ch + 1, bb ^ 1);
        const int j0 = ch * 64;

        short8 kf[2][2], vf[4];
        #pragma unroll
        for (int nt = 0; nt < 2; ++nt)
            #pragma unroll
            for (int ks = 0; ks < 2; ++ks)
                kf[nt][ks] = *(const short8*)&KV[bb][(kh * 2 + nt) * 2 + ks][lane][0];
        #pragma unroll
        for (int nh = 0; nh < 4; ++nh)
            vf[nh] = *(const short8*)&KV[bb][8 + kh * 4 + nh][lane][0];

        floatx4 sa[2];
        sa[0] = (floatx4){0.f, 0.f, 0.f, 0.f};
        sa[1] = (floatx4){0.f, 0.f, 0.f, 0.f};
        #pragma unroll
        for (int nt = 0; nt < 2; ++nt) {
            sa[nt] = __builtin_amdgcn_mfma_f32_16x16x32_bf16(qf0, kf[nt][0], sa[nt], 0, 0, 0);
            sa[nt] = __builtin_amdgcn_mfma_f32_16x16x32_bf16(qf1, kf[nt][1], sa[nt], 0, 0, 0);
        }
        #pragma unroll
        for (int r = 0; r < 4; ++r) {
            const int sq = s0 + rg * 16 + quad * 4 + r;
            #pragma unroll
            for (int nt = 0; nt < 2; ++nt) {
                const int sk = j0 + kh * 32 + nt * 16 + l15;
                float pv = (sk > sq) ? 0.f : __expf(sa[nt][r] * 0.125f - 16.f);
                sa[nt][r] = pv;
                l_i[r] += pv;
            }
        }
        #pragma unroll
        for (int nt = 0; nt < 2; ++nt)
            #pragma unroll
            for (int r = 0; r < 4; ++r)
                Plds[wv][quad * 4 + r][nt * 16 + l15] = f2bf(sa[nt][r]);
        short8 pf = *(const short8*)(&Plds[wv][l15][quad * 8]);
        #pragma unroll
        for (int nh = 0; nh < 4; ++nh)
            o[nh] = __builtin_amdgcn_mfma_f32_16x16x32_bf16(pf, vf[nh], o[nh], 0, 0, 0);

        __syncthreads();
    }

    #pragma unroll
    for (int msk = 1; msk <= 8; msk <<= 1) {
        #pragma unroll
        for (int r = 0; r < 4; ++r)
            l_i[r] += __shfl_xor(l_i[r], msk, 64);
    }

    if (kh == 1) {
        #pragma unroll
        for (int nh = 0; nh < 4; ++nh)
            #pragma unroll
            for (int r = 0; r < 4; ++r)
                oT[rg][quad * 4 + r][nh * 16 + l15] = o[nh][r];
        if (l15 == 0) {
            #pragma unroll
            for (int r = 0; r < 4; ++r)
                lT[rg][quad * 4 + r] = l_i[r];
        }
    }
    __syncthreads();
    if (kh == 0) {
        #pragma unroll
        for (int r = 0; r < 4; ++r) {
            const int row = quad * 4 + r;
            const float inv = 1.f / (l_i[r] + lT[rg][row]);
            #pragma unroll
            for (int nh = 0; nh < 4; ++nh) {
                const int col = nh * 16 + l15;
                out[((long)b * SEQ + s0 + rg * 16 + row) * HEAD + col] =
                    (o[nh][r] + oT[rg][row][col]) * inv;
            }
        }
    }
}

extern "C" void kernel_launch(void* const* d_in, const int* in_sizes, int n_in,
                              void* d_out, int out_size, void* d_ws, size_t ws_size,
                              hipStream_t stream) {
    const float* x  = (const float*)d_in[0];
    const float* Wk = (const float*)d_in[1];
    const float* Wq = (const float*)d_in[2];
    const float* Wv = (const float*)d_in[3];
    float* out = (float*)d_out;

    short* Wf = (short*)d_ws;                          // 384 KiB
    short* q  = Wf + 3 * HEAD * EMB;                   // 2 MiB each
    short* k  = q + (long)BATCH * SEQ * HEAD;
    short* vt = k + (long)BATCH * SEQ * HEAD;

    hipLaunchKernelGGL(wtrans_kernel, dim3(96), dim3(256), 0, stream, Wk, Wq, Wv, Wf);
    hipLaunchKernelGGL(qkv_kernel, dim3(BATCH * SEQ / 16), dim3(256), 0, stream, x, Wf, q, k, vt);
    hipLaunchKernelGGL(attn_kernel, dim3(BATCH * 64), dim3(256), 0, stream, q, k, vt, out);
}